// Round 1
// baseline (368.269 us; speedup 1.0000x reference)
//
#include <hip/hip_runtime.h>

#define T_DIM 512
#define B_DIM 4096
#define F_DIM 16
#define L_DIM 4

// ---------------- fast activations (exact to ~1 ulp of exp/rcp) -------------
__device__ __forceinline__ float fast_sigmoid(float x) {
  // 1 / (1 + e^-x) = rcp(1 + exp2(-x*log2e))
  return __builtin_amdgcn_rcpf(1.0f + __builtin_amdgcn_exp2f(-1.44269504089f * x));
}
__device__ __forceinline__ float fast_tanh(float x) {
  // tanh(x) = 1 - 2/(1 + e^{2x})
  return 1.0f - 2.0f * __builtin_amdgcn_rcpf(1.0f + __builtin_amdgcn_exp2f(2.88539008178f * x));
}

__device__ __forceinline__ void lstm_cell(float gi, float gf, float gg, float go,
                                          float& h, float& c) {
  float i_ = fast_sigmoid(gi);
  float f_ = fast_sigmoid(gf);
  float g_ = fast_tanh(gg);
  float o_ = fast_sigmoid(go);
  c = fmaf(f_, c, i_ * g_);
  h = o_ * fast_tanh(c);
}

// ---------------- phase 1: gx0[t,b,g] = x[t,b,:]·Wih0[g,:] + bih0 + bhh0 ----
__global__ __launch_bounds__(256) void gx0_kernel(
    const float* __restrict__ x, const float* __restrict__ Wih0,
    const float* __restrict__ bih, const float* __restrict__ bhh,
    float4* __restrict__ gx) {
  int idx = blockIdx.x * 256 + threadIdx.x;          // idx = t*B + b, exact grid
  const float4* xr = (const float4*)x + (size_t)idx * 4;
  float4 xv0 = xr[0], xv1 = xr[1], xv2 = xr[2], xv3 = xr[3];
  float xs[16];
  *(float4*)&xs[0]  = xv0; *(float4*)&xs[4]  = xv1;
  *(float4*)&xs[8]  = xv2; *(float4*)&xs[12] = xv3;
  float acc[4];
#pragma unroll
  for (int g = 0; g < 4; ++g) {
    acc[g] = bih[g] + bhh[g];
    const float* w = Wih0 + g * 16;   // uniform address -> scalar loads
#pragma unroll
    for (int i = 0; i < 16; ++i) acc[g] = fmaf(w[i], xs[i], acc[g]);
  }
  gx[idx] = make_float4(acc[0], acc[1], acc[2], acc[3]);
}

// ---------------- phase 2: the recurrent scan, one thread per batch chain ---
template <bool FUSED>
__global__ __launch_bounds__(64) void lstm_scan(
    const float* __restrict__ x,      // [T,B,16] (used when FUSED)
    const float4* __restrict__ gx,    // [T,B] of float4 (used when !FUSED)
    const float* __restrict__ Wih0,   // [4,16]
    const float* __restrict__ Wrest,  // [3,4]
    const float* __restrict__ Whh,    // [4,4]
    const float* __restrict__ bih, const float* __restrict__ bhh,
    float* __restrict__ out) {
  const int b = blockIdx.x * 64 + threadIdx.x;       // 0..4095

  // uniform weights -> scalar registers
  float whh_[4][4];
#pragma unroll
  for (int l = 0; l < 4; ++l)
#pragma unroll
    for (int g = 0; g < 4; ++g) whh_[l][g] = Whh[l * 4 + g];
  float wih_[3][4], base_[3][4];
#pragma unroll
  for (int l = 0; l < 3; ++l)
#pragma unroll
    for (int g = 0; g < 4; ++g) {
      wih_[l][g]  = Wrest[l * 4 + g];
      base_[l][g] = bih[(l + 1) * 4 + g] + bhh[(l + 1) * 4 + g];
    }
  float base0[4];
  float wih0r[4][16];
  if constexpr (FUSED) {
#pragma unroll
    for (int g = 0; g < 4; ++g) {
      base0[g] = bih[g] + bhh[g];
#pragma unroll
      for (int i = 0; i < 16; ++i) wih0r[g][i] = Wih0[g * 16 + i];
    }
  }

  float h[4] = {0.f, 0.f, 0.f, 0.f}, c[4] = {0.f, 0.f, 0.f, 0.f};

  constexpr int CH = FUSED ? 4 : 8;   // prefetch depth (timesteps in flight)
  float4 gbuf[FUSED ? 1 : 8];
  float4 xbuf[FUSED ? 4 : 1][4];

  // preload first CH timesteps
#pragma unroll
  for (int j = 0; j < CH; ++j) {
    if constexpr (!FUSED) {
      gbuf[j] = gx[(size_t)j * B_DIM + b];
    } else {
      const float4* xr = (const float4*)x + ((size_t)j * B_DIM + b) * 4;
      xbuf[j][0] = xr[0]; xbuf[j][1] = xr[1]; xbuf[j][2] = xr[2]; xbuf[j][3] = xr[3];
    }
  }

  for (int t0 = 0; t0 < T_DIM; t0 += CH) {
#pragma unroll
    for (int j = 0; j < CH; ++j) {
      const int t = t0 + j;
      float g0x, g0y, g0z, g0w;
      if constexpr (!FUSED) {
        float4 gq = gbuf[j];
        int tp = t + CH; if (tp > T_DIM - 1) tp = T_DIM - 1;
        gbuf[j] = gx[(size_t)tp * B_DIM + b];        // prefetch, used next chunk
        g0x = gq.x; g0y = gq.y; g0z = gq.z; g0w = gq.w;
      } else {
        float4 xv0 = xbuf[j][0], xv1 = xbuf[j][1], xv2 = xbuf[j][2], xv3 = xbuf[j][3];
        int tp = t + CH; if (tp > T_DIM - 1) tp = T_DIM - 1;
        const float4* xr = (const float4*)x + ((size_t)tp * B_DIM + b) * 4;
        xbuf[j][0] = xr[0]; xbuf[j][1] = xr[1]; xbuf[j][2] = xr[2]; xbuf[j][3] = xr[3];
        float xs[16];
        *(float4*)&xs[0]  = xv0; *(float4*)&xs[4]  = xv1;
        *(float4*)&xs[8]  = xv2; *(float4*)&xs[12] = xv3;
        float a0 = base0[0], a1 = base0[1], a2 = base0[2], a3 = base0[3];
#pragma unroll
        for (int i = 0; i < 16; ++i) {
          float xv = xs[i];
          a0 = fmaf(wih0r[0][i], xv, a0);
          a1 = fmaf(wih0r[1][i], xv, a1);
          a2 = fmaf(wih0r[2][i], xv, a2);
          a3 = fmaf(wih0r[3][i], xv, a3);
        }
        g0x = a0; g0y = a1; g0z = a2; g0w = a3;
      }

      // layer 0: gates = gx0 + whh0 * h0
      lstm_cell(fmaf(whh_[0][0], h[0], g0x),
                fmaf(whh_[0][1], h[0], g0y),
                fmaf(whh_[0][2], h[0], g0z),
                fmaf(whh_[0][3], h[0], g0w), h[0], c[0]);

      // layers 1..3: gates = base + wih * h_{l-1} + whh * h_l
#pragma unroll
      for (int l = 1; l < 4; ++l) {
        float hin = h[l - 1];
        float gi = fmaf(whh_[l][0], h[l], fmaf(wih_[l - 1][0], hin, base_[l - 1][0]));
        float gf = fmaf(whh_[l][1], h[l], fmaf(wih_[l - 1][1], hin, base_[l - 1][1]));
        float gg = fmaf(whh_[l][2], h[l], fmaf(wih_[l - 1][2], hin, base_[l - 1][2]));
        float go = fmaf(whh_[l][3], h[l], fmaf(wih_[l - 1][3], hin, base_[l - 1][3]));
        lstm_cell(gi, gf, gg, go, h[l], c[l]);
      }

      out[(size_t)t * B_DIM + b] = h[3];             // last-layer hidden seq
    }
  }

  // hn, cn
#pragma unroll
  for (int l = 0; l < 4; ++l) {
    out[(size_t)T_DIM * B_DIM + (size_t)l * B_DIM + b] = h[l];
    out[(size_t)T_DIM * B_DIM + (size_t)L_DIM * B_DIM + (size_t)l * B_DIM + b] = c[l];
  }
}

extern "C" void kernel_launch(void* const* d_in, const int* in_sizes, int n_in,
                              void* d_out, int out_size, void* d_ws, size_t ws_size,
                              hipStream_t stream) {
  const float* x     = (const float*)d_in[0];
  const float* Wih0  = (const float*)d_in[1];
  const float* Wrest = (const float*)d_in[2];
  const float* Whh   = (const float*)d_in[3];
  const float* bih   = (const float*)d_in[4];
  const float* bhh   = (const float*)d_in[5];
  float* out = (float*)d_out;

  const size_t gx_bytes = (size_t)T_DIM * B_DIM * 4 * sizeof(float);  // 32 MiB
  if (ws_size >= gx_bytes) {
    float4* gx = (float4*)d_ws;
    gx0_kernel<<<(T_DIM * B_DIM) / 256, 256, 0, stream>>>(x, Wih0, bih, bhh, gx);
    lstm_scan<false><<<B_DIM / 64, 64, 0, stream>>>(x, gx, Wih0, Wrest, Whh, bih, bhh, out);
  } else {
    // fallback: fuse the layer-0 input GEMM into the scan (no workspace needed)
    lstm_scan<true><<<B_DIM / 64, 64, 0, stream>>>(x, nullptr, Wih0, Wrest, Whh, bih, bhh, out);
  }
}

// Round 2
// 285.257 us; speedup vs baseline: 1.2910x; 1.2910x over previous
//
#include <hip/hip_runtime.h>

#define T_DIM 512
#define B_DIM 4096
#define F_DIM 16
#define L_DIM 4

// ---------------- fast activations (exp2/rcp based, ~1 ulp) -----------------
__device__ __forceinline__ float fast_sigmoid(float x) {
  return __builtin_amdgcn_rcpf(1.0f + __builtin_amdgcn_exp2f(-1.44269504089f * x));
}
__device__ __forceinline__ float fast_tanh(float x) {
  return 1.0f - 2.0f * __builtin_amdgcn_rcpf(1.0f + __builtin_amdgcn_exp2f(2.88539008178f * x));
}

// ---------------- phase 1: gx0[t,b,g] = x[t,b,:]·Wih0[g,:] + bih0 + bhh0 ----
__global__ __launch_bounds__(256) void gx0_kernel(
    const float* __restrict__ x, const float* __restrict__ Wih0,
    const float* __restrict__ bih, const float* __restrict__ bhh,
    float4* __restrict__ gx) {
  int idx = blockIdx.x * 256 + threadIdx.x;          // idx = t*B + b, exact grid
  const float4* xr = (const float4*)x + (size_t)idx * 4;
  float4 xv0 = xr[0], xv1 = xr[1], xv2 = xr[2], xv3 = xr[3];
  float xs[16];
  *(float4*)&xs[0]  = xv0; *(float4*)&xs[4]  = xv1;
  *(float4*)&xs[8]  = xv2; *(float4*)&xs[12] = xv3;
  float acc[4];
#pragma unroll
  for (int g = 0; g < 4; ++g) {
    acc[g] = bih[g] + bhh[g];
    const float* w = Wih0 + g * 16;   // uniform address -> scalar loads
#pragma unroll
    for (int i = 0; i < 16; ++i) acc[g] = fmaf(w[i], xs[i], acc[g]);
  }
  gx[idx] = make_float4(acc[0], acc[1], acc[2], acc[3]);
}

// ---------------- phase 2: layer-skewed scan ---------------------------------
// Lane 4*cb + l handles (chain b, layer l) at time t = k - l. h_{l-1}(t) comes
// from lane-1 via __shfl_up (it was produced there in iteration k-1).
// 4096 chains x 4 layers = 16384 threads = 256 waves (4x the unskewed version).
__global__ __launch_bounds__(64) void lstm_scan_skew(
    const float4* __restrict__ gx,    // [T,B] of float4 (i,f,g,o), bias folded
    const float* __restrict__ Wrest,  // [3,4]
    const float* __restrict__ Whh,    // [4,4]
    const float* __restrict__ bih, const float* __restrict__ bhh,
    float* __restrict__ out) {
  const int lane = threadIdx.x;                    // 0..63
  const int l = lane & 3;                          // layer
  const int b = blockIdx.x * 16 + (lane >> 2);     // chain 0..4095
  const bool l0 = (l == 0);
  const float gsel = l0 ? 1.0f : 0.0f;             // gx only feeds layer 0

  // per-lane (layer-indexed) weights
  float wih[4], whh[4], base[4];
#pragma unroll
  for (int g = 0; g < 4; ++g) {
    whh[g]  = Whh[l * 4 + g];
    wih[g]  = l0 ? 0.0f : Wrest[(l - 1) * 4 + g];
    base[g] = l0 ? 0.0f : (bih[l * 4 + g] + bhh[l * 4 + g]);
  }

  float h = 0.f, c = 0.f;

  // 8-deep gx prefetch ring; all 4 lanes of a quad load the same address
  // (hardware broadcast), lanes l>0 mask it out via gsel.
  float4 gbuf[8];
#pragma unroll
  for (int j = 0; j < 8; ++j) gbuf[j] = gx[(size_t)j * B_DIM + b];

  constexpr int K_ITER = T_DIM + 8;                // 520: covers k..T+2, mult of 8
  for (int k0 = 0; k0 < K_ITER; k0 += 8) {
#pragma unroll
    for (int j = 0; j < 8; ++j) {
      const int k = k0 + j;
      const int t = k - l;                         // this lane's timestep
      float4 gq = gbuf[j];
      int tp = k + 8; if (tp > T_DIM - 1) tp = T_DIM - 1;
      gbuf[j] = gx[(size_t)tp * B_DIM + b];        // prefetch for next chunk

      float hin = __shfl_up(h, 1);                 // h_{l-1}(t); garbage at l=0 (wih=0)

      float g0 = fmaf(whh[0], h, fmaf(wih[0], hin, fmaf(gsel, gq.x, base[0])));
      float g1 = fmaf(whh[1], h, fmaf(wih[1], hin, fmaf(gsel, gq.y, base[1])));
      float g2 = fmaf(whh[2], h, fmaf(wih[2], hin, fmaf(gsel, gq.z, base[2])));
      float g3 = fmaf(whh[3], h, fmaf(wih[3], hin, fmaf(gsel, gq.w, base[3])));

      float i_ = fast_sigmoid(g0);
      float f_ = fast_sigmoid(g1);
      float gg = fast_tanh(g2);
      float o_ = fast_sigmoid(g3);
      float cn = fmaf(f_, c, i_ * gg);
      float hn = o_ * fast_tanh(cn);

      const bool valid = (t >= 0) && (t < T_DIM);  // warmup/drain guard
      c = valid ? cn : c;
      h = valid ? hn : h;

      if (l == 3 && valid) out[(size_t)t * B_DIM + b] = h;  // last-layer hidden
    }
  }

  // hn, cn: lane (b,l) holds h_l(T-1), c_l(T-1)
  out[(size_t)T_DIM * B_DIM + (size_t)l * B_DIM + b] = h;
  out[(size_t)T_DIM * B_DIM + (size_t)L_DIM * B_DIM + (size_t)l * B_DIM + b] = c;
}

// ---------------- fallback (no workspace): fused, unskewed -------------------
__global__ __launch_bounds__(64) void lstm_scan_fused(
    const float* __restrict__ x, const float* __restrict__ Wih0,
    const float* __restrict__ Wrest, const float* __restrict__ Whh,
    const float* __restrict__ bih, const float* __restrict__ bhh,
    float* __restrict__ out) {
  const int b = blockIdx.x * 64 + threadIdx.x;
  float whh_[4][4];
#pragma unroll
  for (int l = 0; l < 4; ++l)
#pragma unroll
    for (int g = 0; g < 4; ++g) whh_[l][g] = Whh[l * 4 + g];
  float wih_[3][4], base_[3][4];
#pragma unroll
  for (int l = 0; l < 3; ++l)
#pragma unroll
    for (int g = 0; g < 4; ++g) {
      wih_[l][g]  = Wrest[l * 4 + g];
      base_[l][g] = bih[(l + 1) * 4 + g] + bhh[(l + 1) * 4 + g];
    }
  float base0[4], wih0r[4][16];
#pragma unroll
  for (int g = 0; g < 4; ++g) {
    base0[g] = bih[g] + bhh[g];
#pragma unroll
    for (int i = 0; i < 16; ++i) wih0r[g][i] = Wih0[g * 16 + i];
  }
  float h[4] = {0.f,0.f,0.f,0.f}, c[4] = {0.f,0.f,0.f,0.f};
  for (int t = 0; t < T_DIM; ++t) {
    const float4* xr = (const float4*)x + ((size_t)t * B_DIM + b) * 4;
    float xs[16];
    *(float4*)&xs[0] = xr[0]; *(float4*)&xs[4] = xr[1];
    *(float4*)&xs[8] = xr[2]; *(float4*)&xs[12] = xr[3];
    float a0 = base0[0], a1 = base0[1], a2 = base0[2], a3 = base0[3];
#pragma unroll
    for (int i = 0; i < 16; ++i) {
      a0 = fmaf(wih0r[0][i], xs[i], a0);
      a1 = fmaf(wih0r[1][i], xs[i], a1);
      a2 = fmaf(wih0r[2][i], xs[i], a2);
      a3 = fmaf(wih0r[3][i], xs[i], a3);
    }
    float i_ = fast_sigmoid(fmaf(whh_[0][0], h[0], a0));
    float f_ = fast_sigmoid(fmaf(whh_[0][1], h[0], a1));
    float gg = fast_tanh(fmaf(whh_[0][2], h[0], a2));
    float o_ = fast_sigmoid(fmaf(whh_[0][3], h[0], a3));
    c[0] = fmaf(f_, c[0], i_ * gg);
    h[0] = o_ * fast_tanh(c[0]);
#pragma unroll
    for (int l = 1; l < 4; ++l) {
      float hin = h[l - 1];
      float gi = fmaf(whh_[l][0], h[l], fmaf(wih_[l-1][0], hin, base_[l-1][0]));
      float gf = fmaf(whh_[l][1], h[l], fmaf(wih_[l-1][1], hin, base_[l-1][1]));
      float gG = fmaf(whh_[l][2], h[l], fmaf(wih_[l-1][2], hin, base_[l-1][2]));
      float go = fmaf(whh_[l][3], h[l], fmaf(wih_[l-1][3], hin, base_[l-1][3]));
      float ii = fast_sigmoid(gi), ff = fast_sigmoid(gf);
      float gg2 = fast_tanh(gG), oo = fast_sigmoid(go);
      c[l] = fmaf(ff, c[l], ii * gg2);
      h[l] = oo * fast_tanh(c[l]);
    }
    out[(size_t)t * B_DIM + b] = h[3];
  }
#pragma unroll
  for (int l = 0; l < 4; ++l) {
    out[(size_t)T_DIM * B_DIM + (size_t)l * B_DIM + b] = h[l];
    out[(size_t)T_DIM * B_DIM + (size_t)L_DIM * B_DIM + (size_t)l * B_DIM + b] = c[l];
  }
}

extern "C" void kernel_launch(void* const* d_in, const int* in_sizes, int n_in,
                              void* d_out, int out_size, void* d_ws, size_t ws_size,
                              hipStream_t stream) {
  const float* x     = (const float*)d_in[0];
  const float* Wih0  = (const float*)d_in[1];
  const float* Wrest = (const float*)d_in[2];
  const float* Whh   = (const float*)d_in[3];
  const float* bih   = (const float*)d_in[4];
  const float* bhh   = (const float*)d_in[5];
  float* out = (float*)d_out;

  const size_t gx_bytes = (size_t)T_DIM * B_DIM * 4 * sizeof(float);  // 32 MiB
  if (ws_size >= gx_bytes) {
    float4* gx = (float4*)d_ws;
    gx0_kernel<<<(T_DIM * B_DIM) / 256, 256, 0, stream>>>(x, Wih0, bih, bhh, gx);
    lstm_scan_skew<<<B_DIM / 16, 64, 0, stream>>>(gx, Wrest, Whh, bih, bhh, out);
  } else {
    lstm_scan_fused<<<B_DIM / 64, 64, 0, stream>>>(x, Wih0, Wrest, Whh, bih, bhh, out);
  }
}

// Round 3
// 274.137 us; speedup vs baseline: 1.3434x; 1.0406x over previous
//
#include <hip/hip_runtime.h>

#define T_DIM 512
#define B_DIM 4096
#define F_DIM 16
#define L_DIM 4

// ---------------- fast activations (exp2/rcp based, ~1 ulp) -----------------
__device__ __forceinline__ float fast_sigmoid(float x) {
  return __builtin_amdgcn_rcpf(1.0f + __builtin_amdgcn_exp2f(-1.44269504089f * x));
}
__device__ __forceinline__ float fast_tanh(float x) {
  return 1.0f - 2.0f * __builtin_amdgcn_rcpf(1.0f + __builtin_amdgcn_exp2f(2.88539008178f * x));
}

// lane(i) <- lane(i-1) within 16-lane DPP rows; 2-cycle VALU op, stays off the
// LDS pipe (vs ds_bpermute for __shfl_up). Row-boundary lanes (0,16,32,48) get
// 0 (bound_ctrl) — those are all l=0 lanes which ignore hin anyway.
__device__ __forceinline__ float dpp_prev(float v) {
  int r = __builtin_amdgcn_update_dpp(0, __builtin_bit_cast(int, v),
                                      0x111 /*row_shr:1*/, 0xf, 0xf, true);
  return __builtin_bit_cast(float, r);
}

// ---------------- phase 1: gx0[t,b,g] = x[t,b,:]·Wih0[g,:] + bih0 + bhh0 ----
__global__ __launch_bounds__(256) void gx0_kernel(
    const float* __restrict__ x, const float* __restrict__ Wih0,
    const float* __restrict__ bih, const float* __restrict__ bhh,
    float4* __restrict__ gx) {
  int idx = blockIdx.x * 256 + threadIdx.x;          // idx = t*B + b, exact grid
  const float4* xr = (const float4*)x + (size_t)idx * 4;
  float4 xv0 = xr[0], xv1 = xr[1], xv2 = xr[2], xv3 = xr[3];
  float xs[16];
  *(float4*)&xs[0]  = xv0; *(float4*)&xs[4]  = xv1;
  *(float4*)&xs[8]  = xv2; *(float4*)&xs[12] = xv3;
  float acc[4];
#pragma unroll
  for (int g = 0; g < 4; ++g) {
    acc[g] = bih[g] + bhh[g];
    const float* w = Wih0 + g * 16;   // uniform address -> scalar loads
#pragma unroll
    for (int i = 0; i < 16; ++i) acc[g] = fmaf(w[i], xs[i], acc[g]);
  }
  gx[idx] = make_float4(acc[0], acc[1], acc[2], acc[3]);
}

// ---------------- phase 2: layer-skewed scan ---------------------------------
// Lane 4*cb + l handles (chain b, layer l) at time t = k - l. h_{l-1}(t) comes
// from lane-1 via DPP row_shr:1 (produced there in iteration k-1).
// 4096 chains x 4 layers = 16384 threads = 256 waves.
__global__ __launch_bounds__(64) void lstm_scan_skew(
    const float4* __restrict__ gx,    // [T,B] of float4 (i,f,g,o), bias folded
    const float* __restrict__ Wrest,  // [3,4]
    const float* __restrict__ Whh,    // [4,4]
    const float* __restrict__ bih, const float* __restrict__ bhh,
    float* __restrict__ out) {
  const int lane = threadIdx.x;                    // 0..63
  const int l = lane & 3;                          // layer
  const int b = blockIdx.x * 16 + (lane >> 2);     // chain 0..4095
  const bool l0 = (l == 0);
  const float gsel = l0 ? 1.0f : 0.0f;             // gx only feeds layer 0

  float wih[4], whh[4], base[4];
#pragma unroll
  for (int g = 0; g < 4; ++g) {
    whh[g]  = Whh[l * 4 + g];
    wih[g]  = l0 ? 0.0f : Wrest[(l - 1) * 4 + g];
    base[g] = l0 ? 0.0f : (bih[l * 4 + g] + bhh[l * 4 + g]);
  }

  float h = 0.f, c = 0.f;

  // 8-deep gx prefetch ring; the 4 lanes of a quad load the same address
  // (hardware broadcast), lanes l>0 mask it via gsel.
  float4 gbuf[8];
#pragma unroll
  for (int j = 0; j < 8; ++j) gbuf[j] = gx[(size_t)j * B_DIM + b];

  // One step. `guard` is a compile-time constant at every call site.
  auto cell = [&](int k, int j, bool guard) {
    float4 gq = gbuf[j];
    int tp = k + 8; tp = tp < T_DIM - 1 ? tp : T_DIM - 1;
    gbuf[j] = gx[(size_t)tp * B_DIM + b];          // prefetch for next chunk

    float hin = dpp_prev(h);                       // h_{l-1}(t)

    float g0 = fmaf(whh[0], h, fmaf(wih[0], hin, fmaf(gsel, gq.x, base[0])));
    float g1 = fmaf(whh[1], h, fmaf(wih[1], hin, fmaf(gsel, gq.y, base[1])));
    float g2 = fmaf(whh[2], h, fmaf(wih[2], hin, fmaf(gsel, gq.z, base[2])));
    float g3 = fmaf(whh[3], h, fmaf(wih[3], hin, fmaf(gsel, gq.w, base[3])));

    float i_ = fast_sigmoid(g0);
    float f_ = fast_sigmoid(g1);
    float gg = fast_tanh(g2);
    float o_ = fast_sigmoid(g3);
    float cn = fmaf(f_, c, i_ * gg);
    float hn = o_ * fast_tanh(cn);

    if (guard) {
      const int t = k - l;
      const bool valid = (unsigned)t < (unsigned)T_DIM;
      c = valid ? cn : c;
      h = valid ? hn : h;
      if (l == 3 && valid) out[(size_t)t * B_DIM + b] = hn;
    } else {
      c = cn;
      h = hn;
      if (l == 3) out[(size_t)(k - 3) * B_DIM + b] = hn;
    }
  };

  // warm-up: k=0..7 (some lanes still at t<0)
#pragma unroll
  for (int j = 0; j < 8; ++j) cell(j, j, true);
  // body: k=8..511 — every lane's t=k-l is in [0,511]; no guards
  for (int k0 = 8; k0 < T_DIM; k0 += 8) {
#pragma unroll
    for (int j = 0; j < 8; ++j) cell(k0 + j, j, false);
  }
  // drain: k=512..519 (lanes l>0 finish t=509..511)
#pragma unroll
  for (int j = 0; j < 8; ++j) cell(T_DIM + j, j, true);

  // hn, cn: lane (b,l) holds h_l(T-1), c_l(T-1)
  out[(size_t)T_DIM * B_DIM + (size_t)l * B_DIM + b] = h;
  out[(size_t)T_DIM * B_DIM + (size_t)L_DIM * B_DIM + (size_t)l * B_DIM + b] = c;
}

// ---------------- fallback (no workspace): fused, unskewed -------------------
__global__ __launch_bounds__(64) void lstm_scan_fused(
    const float* __restrict__ x, const float* __restrict__ Wih0,
    const float* __restrict__ Wrest, const float* __restrict__ Whh,
    const float* __restrict__ bih, const float* __restrict__ bhh,
    float* __restrict__ out) {
  const int b = blockIdx.x * 64 + threadIdx.x;
  float whh_[4][4];
#pragma unroll
  for (int l = 0; l < 4; ++l)
#pragma unroll
    for (int g = 0; g < 4; ++g) whh_[l][g] = Whh[l * 4 + g];
  float wih_[3][4], base_[3][4];
#pragma unroll
  for (int l = 0; l < 3; ++l)
#pragma unroll
    for (int g = 0; g < 4; ++g) {
      wih_[l][g]  = Wrest[l * 4 + g];
      base_[l][g] = bih[(l + 1) * 4 + g] + bhh[(l + 1) * 4 + g];
    }
  float base0[4], wih0r[4][16];
#pragma unroll
  for (int g = 0; g < 4; ++g) {
    base0[g] = bih[g] + bhh[g];
#pragma unroll
    for (int i = 0; i < 16; ++i) wih0r[g][i] = Wih0[g * 16 + i];
  }
  float h[4] = {0.f,0.f,0.f,0.f}, c[4] = {0.f,0.f,0.f,0.f};
  for (int t = 0; t < T_DIM; ++t) {
    const float4* xr = (const float4*)x + ((size_t)t * B_DIM + b) * 4;
    float xs[16];
    *(float4*)&xs[0] = xr[0]; *(float4*)&xs[4] = xr[1];
    *(float4*)&xs[8] = xr[2]; *(float4*)&xs[12] = xr[3];
    float a0 = base0[0], a1 = base0[1], a2 = base0[2], a3 = base0[3];
#pragma unroll
    for (int i = 0; i < 16; ++i) {
      a0 = fmaf(wih0r[0][i], xs[i], a0);
      a1 = fmaf(wih0r[1][i], xs[i], a1);
      a2 = fmaf(wih0r[2][i], xs[i], a2);
      a3 = fmaf(wih0r[3][i], xs[i], a3);
    }
    float i_ = fast_sigmoid(fmaf(whh_[0][0], h[0], a0));
    float f_ = fast_sigmoid(fmaf(whh_[0][1], h[0], a1));
    float gg = fast_tanh(fmaf(whh_[0][2], h[0], a2));
    float o_ = fast_sigmoid(fmaf(whh_[0][3], h[0], a3));
    c[0] = fmaf(f_, c[0], i_ * gg);
    h[0] = o_ * fast_tanh(c[0]);
#pragma unroll
    for (int l = 1; l < 4; ++l) {
      float hin = h[l - 1];
      float gi = fmaf(whh_[l][0], h[l], fmaf(wih_[l-1][0], hin, base_[l-1][0]));
      float gf = fmaf(whh_[l][1], h[l], fmaf(wih_[l-1][1], hin, base_[l-1][1]));
      float gG = fmaf(whh_[l][2], h[l], fmaf(wih_[l-1][2], hin, base_[l-1][2]));
      float go = fmaf(whh_[l][3], h[l], fmaf(wih_[l-1][3], hin, base_[l-1][3]));
      float ii = fast_sigmoid(gi), ff = fast_sigmoid(gf);
      float gg2 = fast_tanh(gG), oo = fast_sigmoid(go);
      c[l] = fmaf(ff, c[l], ii * gg2);
      h[l] = oo * fast_tanh(c[l]);
    }
    out[(size_t)t * B_DIM + b] = h[3];
  }
#pragma unroll
  for (int l = 0; l < 4; ++l) {
    out[(size_t)T_DIM * B_DIM + (size_t)l * B_DIM + b] = h[l];
    out[(size_t)T_DIM * B_DIM + (size_t)L_DIM * B_DIM + (size_t)l * B_DIM + b] = c[l];
  }
}

extern "C" void kernel_launch(void* const* d_in, const int* in_sizes, int n_in,
                              void* d_out, int out_size, void* d_ws, size_t ws_size,
                              hipStream_t stream) {
  const float* x     = (const float*)d_in[0];
  const float* Wih0  = (const float*)d_in[1];
  const float* Wrest = (const float*)d_in[2];
  const float* Whh   = (const float*)d_in[3];
  const float* bih   = (const float*)d_in[4];
  const float* bhh   = (const float*)d_in[5];
  float* out = (float*)d_out;

  const size_t gx_bytes = (size_t)T_DIM * B_DIM * 4 * sizeof(float);  // 32 MiB
  if (ws_size >= gx_bytes) {
    float4* gx = (float4*)d_ws;
    gx0_kernel<<<(T_DIM * B_DIM) / 256, 256, 0, stream>>>(x, Wih0, bih, bhh, gx);
    lstm_scan_skew<<<B_DIM / 16, 64, 0, stream>>>(gx, Wrest, Whh, bih, bhh, out);
  } else {
    lstm_scan_fused<<<B_DIM / 64, 64, 0, stream>>>(x, Wih0, Wrest, Whh, bih, bhh, out);
  }
}